// Round 4
// baseline (2042.436 us; speedup 1.0000x reference)
//
#include <hip/hip_runtime.h>

#define NROI 1024
#define NPTS 49
#define NCH  256

__global__ __launch_bounds__(256) void mpe_kernel(
    const float* __restrict__ f0, const float* __restrict__ f1,
    const float* __restrict__ f2, const float* __restrict__ f3,
    const float* __restrict__ rois, const float* __restrict__ points,
    float* __restrict__ out)
{
    const int np = blockIdx.x;          // n * NPTS + p
    const int n  = np / NPTS;
    const int p  = np - n * NPTS;
    const int c  = threadIdx.x;         // channel 0..255

    // roi (broadcast loads, same addr across lanes)
    const float bi  = rois[n * 5 + 0];
    const float rx1 = rois[n * 5 + 1];
    const float ry1 = rois[n * 5 + 2];
    const float rx2 = rois[n * 5 + 3];
    const float ry2 = rois[n * 5 + 4];
    const int   b   = (int)bi;

    const float px = points[(size_t)np * 2 + 0];
    const float py = points[(size_t)np * 2 + 1];

    // image-space coordinate of this point
    const float cx = rx1 + px * (rx2 - rx1);
    const float cy = ry1 + py * (ry2 - ry1);

    const float* feats[4] = {f0, f1, f2, f3};
    const int   Hs[4]   = {200, 100, 50, 25};
    const int   Ws[4]   = {336, 168, 84, 42};
    const float invS[4] = {0.25f, 0.125f, 0.0625f, 0.03125f};

#pragma unroll
    for (int L = 0; L < 4; ++L) {
        const int H = Hs[L], W = Ws[L];
        // grid_sample align_corners=False unnormalize collapses to coord/stride - 0.5
        const float x = cx * invS[L] - 0.5f;
        const float y = cy * invS[L] - 0.5f;

        const float x0f = floorf(x);
        const float y0f = floorf(y);
        const float wx1 = x - x0f, wx0 = 1.0f - wx1;
        const float wy1 = y - y0f, wy0 = 1.0f - wy1;

        const float x1f = x0f + 1.0f;
        const float y1f = y0f + 1.0f;

        const float vx0 = (x0f >= 0.0f && x0f <= (float)(W - 1)) ? 1.0f : 0.0f;
        const float vx1 = (x1f >= 0.0f && x1f <= (float)(W - 1)) ? 1.0f : 0.0f;
        const float vy0 = (y0f >= 0.0f && y0f <= (float)(H - 1)) ? 1.0f : 0.0f;
        const float vy1 = (y1f >= 0.0f && y1f <= (float)(H - 1)) ? 1.0f : 0.0f;

        const int x0 = min(max((int)x0f, 0), W - 1);
        const int x1 = min(max((int)x1f, 0), W - 1);
        const int y0 = min(max((int)y0f, 0), H - 1);
        const int y1 = min(max((int)y1f, 0), H - 1);

        const float* base = feats[L] + ((size_t)b * NCH + c) * (size_t)(H * W);

        const float v00 = base[y0 * W + x0];
        const float v01 = base[y0 * W + x1];
        const float v10 = base[y1 * W + x0];
        const float v11 = base[y1 * W + x1];

        const float acc = v00 * (wx0 * wy0 * vx0 * vy0)
                        + v01 * (wx1 * wy0 * vx1 * vy0)
                        + v10 * (wx0 * wy1 * vx0 * vy1)
                        + v11 * (wx1 * wy1 * vx1 * vy1);

        out[((size_t)n * 1024 + (size_t)L * NCH + c) * NPTS + p] = acc;
    }
}

extern "C" void kernel_launch(void* const* d_in, const int* in_sizes, int n_in,
                              void* d_out, int out_size, void* d_ws, size_t ws_size,
                              hipStream_t stream)
{
    const float* f0     = (const float*)d_in[0];
    const float* f1     = (const float*)d_in[1];
    const float* f2     = (const float*)d_in[2];
    const float* f3     = (const float*)d_in[3];
    const float* rois   = (const float*)d_in[4];
    const float* points = (const float*)d_in[5];
    float*       out    = (float*)d_out;

    dim3 grid(NROI * NPTS);
    dim3 block(NCH);
    mpe_kernel<<<grid, block, 0, stream>>>(f0, f1, f2, f3, rois, points, out);
}

// Round 5
// 278.787 us; speedup vs baseline: 7.3261x; 7.3261x over previous
//
#include <hip/hip_runtime.h>

#define NROI 1024
#define NPTS 49
#define NCH  256

// Level geometry
// L:      0      1     2     3
// H:    200    100    50    25
// W:    336    168    84    42
// HW: 67200  16800  4200  1050   (sum 89250; B=2, C=256 -> 45,696,000 floats ws)

// ---------------- transpose [B][C][HW] -> [B][HW][C] ----------------
__global__ __launch_bounds__(256) void transpose_kernel(
    const float* __restrict__ in, float* __restrict__ out, int HW)
{
    __shared__ float tile[64][65];
    const int hw0 = blockIdx.x * 64;
    const int c0  = blockIdx.y * 64;
    const int b   = blockIdx.z;
    const int tx  = threadIdx.x & 63;
    const int ty  = threadIdx.x >> 6;           // 0..3
    const float* ib = in  + (size_t)b * NCH * HW;
    float*       ob = out + (size_t)b * HW * NCH;
#pragma unroll
    for (int r = ty; r < 64; r += 4) {
        const int hw = hw0 + tx;
        if (hw < HW) tile[r][tx] = ib[(size_t)(c0 + r) * HW + hw];
    }
    __syncthreads();
#pragma unroll
    for (int r = ty; r < 64; r += 4) {
        const int hw = hw0 + r;
        if (hw < HW) ob[(size_t)hw * NCH + c0 + tx] = tile[tx][r];
    }
}

// ---------------- bilinear sample from [B][H][W][C] ----------------
// One block per (roi, c-half). Computes a [128 c x 49 p] tile in LDS,
// then writes it as one contiguous 25 KB chunk (out is c-major, p-minor).
__global__ __launch_bounds__(256) void sample_kernel(
    const float* __restrict__ ft,   // this level, [B][H][W][C]
    const float* __restrict__ rois,
    const float* __restrict__ points,
    float* __restrict__ out,        // [N][1024][49]
    int H, int W, float invS, int cbase)
{
    __shared__ float tile[128 * NPTS];
    const int n    = blockIdx.x >> 1;
    const int half = blockIdx.x & 1;
    const int cl   = threadIdx.x & 127;         // local channel 0..127
    const int c    = cl + half * 128;
    const int pg   = threadIdx.x >> 7;          // 0/1 : p-interleave group

    const float bi  = rois[n * 5 + 0];
    const float rx1 = rois[n * 5 + 1];
    const float ry1 = rois[n * 5 + 2];
    const float rx2 = rois[n * 5 + 3];
    const float ry2 = rois[n * 5 + 4];
    const int   b   = (int)bi;

    const float* fb = ft + (size_t)b * H * W * NCH;

    for (int p = pg; p < NPTS; p += 2) {
        const float px = points[((size_t)n * NPTS + p) * 2 + 0];
        const float py = points[((size_t)n * NPTS + p) * 2 + 1];
        const float cx = rx1 + px * (rx2 - rx1);
        const float cy = ry1 + py * (ry2 - ry1);

        // grid_sample align_corners=False collapses to coord/stride - 0.5
        const float x = cx * invS - 0.5f;
        const float y = cy * invS - 0.5f;

        const float x0f = floorf(x);
        const float y0f = floorf(y);
        const float wx1 = x - x0f, wx0 = 1.0f - wx1;
        const float wy1 = y - y0f, wy0 = 1.0f - wy1;
        const float x1f = x0f + 1.0f;
        const float y1f = y0f + 1.0f;

        const float vx0 = (x0f >= 0.0f && x0f <= (float)(W - 1)) ? 1.0f : 0.0f;
        const float vx1 = (x1f >= 0.0f && x1f <= (float)(W - 1)) ? 1.0f : 0.0f;
        const float vy0 = (y0f >= 0.0f && y0f <= (float)(H - 1)) ? 1.0f : 0.0f;
        const float vy1 = (y1f >= 0.0f && y1f <= (float)(H - 1)) ? 1.0f : 0.0f;

        const int x0 = min(max((int)x0f, 0), W - 1);
        const int x1 = min(max((int)x1f, 0), W - 1);
        const int y0 = min(max((int)y0f, 0), H - 1);
        const int y1 = min(max((int)y1f, 0), H - 1);

        // coalesced taps: 64 lanes read 64 consecutive channels (256 B)
        const float v00 = fb[((size_t)y0 * W + x0) * NCH + c];
        const float v01 = fb[((size_t)y0 * W + x1) * NCH + c];
        const float v10 = fb[((size_t)y1 * W + x0) * NCH + c];
        const float v11 = fb[((size_t)y1 * W + x1) * NCH + c];

        const float acc = v00 * (wx0 * wy0 * vx0 * vy0)
                        + v01 * (wx1 * wy0 * vx1 * vy0)
                        + v10 * (wx0 * wy1 * vx0 * vy1)
                        + v11 * (wx1 * wy1 * vx1 * vy1);

        // stride-49 LDS store: 49 % 32 = 17, gcd(17,32)=1 -> conflict-free
        tile[cl * NPTS + p] = acc;
    }
    __syncthreads();

    // contiguous write of the [128 x 49] tile
    float* ob = out + ((size_t)n * 1024 + cbase + half * 128) * NPTS;
    for (int i = threadIdx.x; i < 128 * NPTS; i += 256)
        ob[i] = tile[i];
}

// ---------------- fallback: direct BCHW sampling (round-4 verified) ----------------
__global__ __launch_bounds__(256) void mpe_kernel(
    const float* __restrict__ f0, const float* __restrict__ f1,
    const float* __restrict__ f2, const float* __restrict__ f3,
    const float* __restrict__ rois, const float* __restrict__ points,
    float* __restrict__ out)
{
    const int np = blockIdx.x;
    const int n  = np / NPTS;
    const int p  = np - n * NPTS;
    const int c  = threadIdx.x;

    const float bi  = rois[n * 5 + 0];
    const float rx1 = rois[n * 5 + 1];
    const float ry1 = rois[n * 5 + 2];
    const float rx2 = rois[n * 5 + 3];
    const float ry2 = rois[n * 5 + 4];
    const int   b   = (int)bi;

    const float px = points[(size_t)np * 2 + 0];
    const float py = points[(size_t)np * 2 + 1];
    const float cx = rx1 + px * (rx2 - rx1);
    const float cy = ry1 + py * (ry2 - ry1);

    const float* feats[4] = {f0, f1, f2, f3};
    const int   Hs[4]   = {200, 100, 50, 25};
    const int   Ws[4]   = {336, 168, 84, 42};
    const float invS[4] = {0.25f, 0.125f, 0.0625f, 0.03125f};

#pragma unroll
    for (int L = 0; L < 4; ++L) {
        const int H = Hs[L], W = Ws[L];
        const float x = cx * invS[L] - 0.5f;
        const float y = cy * invS[L] - 0.5f;
        const float x0f = floorf(x), y0f = floorf(y);
        const float wx1 = x - x0f, wx0 = 1.0f - wx1;
        const float wy1 = y - y0f, wy0 = 1.0f - wy1;
        const float x1f = x0f + 1.0f, y1f = y0f + 1.0f;
        const float vx0 = (x0f >= 0.0f && x0f <= (float)(W - 1)) ? 1.0f : 0.0f;
        const float vx1 = (x1f >= 0.0f && x1f <= (float)(W - 1)) ? 1.0f : 0.0f;
        const float vy0 = (y0f >= 0.0f && y0f <= (float)(H - 1)) ? 1.0f : 0.0f;
        const float vy1 = (y1f >= 0.0f && y1f <= (float)(H - 1)) ? 1.0f : 0.0f;
        const int x0 = min(max((int)x0f, 0), W - 1);
        const int x1 = min(max((int)x1f, 0), W - 1);
        const int y0 = min(max((int)y0f, 0), H - 1);
        const int y1 = min(max((int)y1f, 0), H - 1);
        const float* base = feats[L] + ((size_t)b * NCH + c) * (size_t)(H * W);
        const float acc = base[y0 * W + x0] * (wx0 * wy0 * vx0 * vy0)
                        + base[y0 * W + x1] * (wx1 * wy0 * vx1 * vy0)
                        + base[y1 * W + x0] * (wx0 * wy1 * vx0 * vy1)
                        + base[y1 * W + x1] * (wx1 * wy1 * vx1 * vy1);
        out[((size_t)n * 1024 + (size_t)L * NCH + c) * NPTS + p] = acc;
    }
}

extern "C" void kernel_launch(void* const* d_in, const int* in_sizes, int n_in,
                              void* d_out, int out_size, void* d_ws, size_t ws_size,
                              hipStream_t stream)
{
    const float* f0     = (const float*)d_in[0];
    const float* f1     = (const float*)d_in[1];
    const float* f2     = (const float*)d_in[2];
    const float* f3     = (const float*)d_in[3];
    const float* rois   = (const float*)d_in[4];
    const float* points = (const float*)d_in[5];
    float*       out    = (float*)d_out;

    const size_t WS_NEED = 45696000ull * 4ull;  // 182.8 MB (f32 HWC copy of all levels)

    if (ws_size >= WS_NEED) {
        float* ws = (float*)d_ws;
        float* t0 = ws;                  // [2][67200][256]
        float* t1 = ws + 34406400ull;    // [2][16800][256]
        float* t2 = ws + 43008000ull;    // [2][ 4200][256]
        float* t3 = ws + 45158400ull;    // [2][ 1050][256]

        transpose_kernel<<<dim3(1050, 4, 2), 256, 0, stream>>>(f0, t0, 67200);
        transpose_kernel<<<dim3( 263, 4, 2), 256, 0, stream>>>(f1, t1, 16800);
        transpose_kernel<<<dim3(  66, 4, 2), 256, 0, stream>>>(f2, t2,  4200);
        transpose_kernel<<<dim3(  17, 4, 2), 256, 0, stream>>>(f3, t3,  1050);

        const dim3 g(NROI * 2);
        sample_kernel<<<g, 256, 0, stream>>>(t0, rois, points, out, 200, 336, 0.25f,    0);
        sample_kernel<<<g, 256, 0, stream>>>(t1, rois, points, out, 100, 168, 0.125f, 256);
        sample_kernel<<<g, 256, 0, stream>>>(t2, rois, points, out,  50,  84, 0.0625f, 512);
        sample_kernel<<<g, 256, 0, stream>>>(t3, rois, points, out,  25,  42, 0.03125f, 768);
    } else {
        mpe_kernel<<<dim3(NROI * NPTS), 256, 0, stream>>>(f0, f1, f2, f3, rois, points, out);
    }
}

// Round 7
// 176.934 us; speedup vs baseline: 11.5435x; 1.5757x over previous
//
#include <hip/hip_runtime.h>
#include <hip/hip_bf16.h>

#define NROI 1024
#define NPTS 49
#define NCH  256

// Level geometry:  L: 0      1     2     3
//                  H: 200    100   50    25
//                  W: 336    168   84    42
//                 HW: 67200  16800 4200  1050
// bf16 ws offsets (elements): t0=0, t1=34406400, t2=43008000, t3=45158400
// total 45,696,000 bf16 = 91.4 MB

__device__ __forceinline__ float bflo(unsigned u) { return __uint_as_float(u << 16); }
__device__ __forceinline__ float bfhi(unsigned u) { return __uint_as_float(u & 0xffff0000u); }

// ---------------- fused transpose: [B][C][HW] f32 -> [B][HW][C] bf16 ----------------
__global__ __launch_bounds__(256) void transpose_all(
    const float* __restrict__ f0, const float* __restrict__ f1,
    const float* __restrict__ f2, const float* __restrict__ f3,
    __hip_bfloat16* __restrict__ ws)
{
    int bid = blockIdx.x;
    const float* in;
    __hip_bfloat16* outp;
    int HW;
    if (bid < 8400)       { in = f0; outp = ws;            HW = 67200; }
    else if (bid < 10504) { bid -= 8400;  in = f1; outp = ws + 34406400; HW = 16800; }
    else if (bid < 11032) { bid -= 10504; in = f2; outp = ws + 43008000; HW = 4200;  }
    else                  { bid -= 11032; in = f3; outp = ws + 45158400; HW = 1050;  }
    const int hwc = bid >> 3;
    const int rem = bid & 7;
    const int c0  = (rem >> 1) * 64;
    const int b   = rem & 1;
    const int hw0 = hwc * 64;

    __shared__ float tile[64][65];
    const int tx = threadIdx.x & 63;
    const int ty = threadIdx.x >> 6;            // 0..3
    const float* ib       = in   + (size_t)b * NCH * HW;
    __hip_bfloat16* ob    = outp + (size_t)b * HW * NCH;

#pragma unroll
    for (int r = ty; r < 64; r += 4) {
        const int hw = hw0 + tx;
        if (hw < HW) tile[r][tx] = ib[(size_t)(c0 + r) * HW + hw];
    }
    __syncthreads();
#pragma unroll
    for (int r = ty; r < 64; r += 4) {
        const int hw = hw0 + r;
        if (hw < HW) ob[(size_t)hw * NCH + c0 + tx] = __float2bfloat16(tile[tx][r]);
    }
}

// ---------------- fused sample: all (roi, level) pairs ----------------
// block = (n, L); 256 threads = 64 channel-quads x 4 point-groups.
// Taps are 8 B uint2 (4 bf16 channels) -> 512 B contiguous per wave.
__global__ __launch_bounds__(256) void sample_all(
    const __hip_bfloat16* __restrict__ ws,
    const float* __restrict__ rois,
    const float* __restrict__ points,
    float* __restrict__ out)
{
    __shared__ __align__(16) float tile[NCH * NPTS];   // 50176 B

    const int n = blockIdx.x >> 2;
    const int L = blockIdx.x & 3;

    const __hip_bfloat16* ft;
    int H, W;
    float invS;
    if (L == 0)      { ft = ws;            H = 200; W = 336; invS = 0.25f;    }
    else if (L == 1) { ft = ws + 34406400; H = 100; W = 168; invS = 0.125f;   }
    else if (L == 2) { ft = ws + 43008000; H = 50;  W = 84;  invS = 0.0625f;  }
    else             { ft = ws + 45158400; H = 25;  W = 42;  invS = 0.03125f; }

    const int c4 = (threadIdx.x & 63) * 4;       // first of 4 channels
    const int pg = threadIdx.x >> 6;             // point group 0..3

    const float bi  = rois[n * 5 + 0];
    const float rx1 = rois[n * 5 + 1];
    const float ry1 = rois[n * 5 + 2];
    const float rx2 = rois[n * 5 + 3];
    const float ry2 = rois[n * 5 + 4];
    const int   b   = (int)bi;

    const unsigned short* fb =
        (const unsigned short*)(ft + (size_t)b * H * W * NCH);

    for (int p = pg; p < NPTS; p += 4) {
        const float px = points[((size_t)n * NPTS + p) * 2 + 0];
        const float py = points[((size_t)n * NPTS + p) * 2 + 1];
        const float cx = rx1 + px * (rx2 - rx1);
        const float cy = ry1 + py * (ry2 - ry1);

        // grid_sample align_corners=False collapses to coord/stride - 0.5
        const float x = cx * invS - 0.5f;
        const float y = cy * invS - 0.5f;

        const float x0f = floorf(x), y0f = floorf(y);
        const float wx1 = x - x0f, wx0 = 1.0f - wx1;
        const float wy1 = y - y0f, wy0 = 1.0f - wy1;
        const float x1f = x0f + 1.0f, y1f = y0f + 1.0f;

        const float vx0 = (x0f >= 0.0f && x0f <= (float)(W - 1)) ? 1.0f : 0.0f;
        const float vx1 = (x1f >= 0.0f && x1f <= (float)(W - 1)) ? 1.0f : 0.0f;
        const float vy0 = (y0f >= 0.0f && y0f <= (float)(H - 1)) ? 1.0f : 0.0f;
        const float vy1 = (y1f >= 0.0f && y1f <= (float)(H - 1)) ? 1.0f : 0.0f;

        const int x0 = min(max((int)x0f, 0), W - 1);
        const int x1 = min(max((int)x1f, 0), W - 1);
        const int y0 = min(max((int)y0f, 0), H - 1);
        const int y1 = min(max((int)y1f, 0), H - 1);

        const float w00 = wx0 * wy0 * vx0 * vy0;
        const float w01 = wx1 * wy0 * vx1 * vy0;
        const float w10 = wx0 * wy1 * vx0 * vy1;
        const float w11 = wx1 * wy1 * vx1 * vy1;

        const uint2 u00 = *(const uint2*)(fb + ((size_t)y0 * W + x0) * NCH + c4);
        const uint2 u01 = *(const uint2*)(fb + ((size_t)y0 * W + x1) * NCH + c4);
        const uint2 u10 = *(const uint2*)(fb + ((size_t)y1 * W + x0) * NCH + c4);
        const uint2 u11 = *(const uint2*)(fb + ((size_t)y1 * W + x1) * NCH + c4);

        const float a0 = bflo(u00.x) * w00 + bflo(u01.x) * w01 + bflo(u10.x) * w10 + bflo(u11.x) * w11;
        const float a1 = bfhi(u00.x) * w00 + bfhi(u01.x) * w01 + bfhi(u10.x) * w10 + bfhi(u11.x) * w11;
        const float a2 = bflo(u00.y) * w00 + bflo(u01.y) * w01 + bflo(u10.y) * w10 + bflo(u11.y) * w11;
        const float a3 = bfhi(u00.y) * w00 + bfhi(u01.y) * w01 + bfhi(u10.y) * w10 + bfhi(u11.y) * w11;

        tile[(c4 + 0) * NPTS + p] = a0;
        tile[(c4 + 1) * NPTS + p] = a1;
        tile[(c4 + 2) * NPTS + p] = a2;
        tile[(c4 + 3) * NPTS + p] = a3;
    }
    __syncthreads();

    // contiguous 50 KB write of the [256 x 49] block tile
    const float4* t4 = (const float4*)tile;
    float4* o4 = (float4*)(out + ((size_t)n * 1024 + (size_t)L * NCH) * NPTS);
#pragma unroll 4
    for (int i = threadIdx.x; i < (NCH * NPTS) / 4; i += 256)
        o4[i] = t4[i];
}

// ---------------- fallback: direct BCHW sampling (round-4 verified) ----------------
__global__ __launch_bounds__(256) void mpe_kernel(
    const float* __restrict__ f0, const float* __restrict__ f1,
    const float* __restrict__ f2, const float* __restrict__ f3,
    const float* __restrict__ rois, const float* __restrict__ points,
    float* __restrict__ out)
{
    const int np = blockIdx.x;
    const int n  = np / NPTS;
    const int p  = np - n * NPTS;
    const int c  = threadIdx.x;

    const float bi  = rois[n * 5 + 0];
    const float rx1 = rois[n * 5 + 1];
    const float ry1 = rois[n * 5 + 2];
    const float rx2 = rois[n * 5 + 3];
    const float ry2 = rois[n * 5 + 4];
    const int   b   = (int)bi;

    const float px = points[(size_t)np * 2 + 0];
    const float py = points[(size_t)np * 2 + 1];
    const float cx = rx1 + px * (rx2 - rx1);
    const float cy = ry1 + py * (ry2 - ry1);

    const float* feats[4] = {f0, f1, f2, f3};
    const int   Hs[4]   = {200, 100, 50, 25};
    const int   Ws[4]   = {336, 168, 84, 42};
    const float invS[4] = {0.25f, 0.125f, 0.0625f, 0.03125f};

#pragma unroll
    for (int L = 0; L < 4; ++L) {
        const int H = Hs[L], W = Ws[L];
        const float x = cx * invS[L] - 0.5f;
        const float y = cy * invS[L] - 0.5f;
        const float x0f = floorf(x), y0f = floorf(y);
        const float wx1 = x - x0f, wx0 = 1.0f - wx1;
        const float wy1 = y - y0f, wy0 = 1.0f - wy1;
        const float x1f = x0f + 1.0f, y1f = y0f + 1.0f;
        const float vx0 = (x0f >= 0.0f && x0f <= (float)(W - 1)) ? 1.0f : 0.0f;
        const float vx1 = (x1f >= 0.0f && x1f <= (float)(W - 1)) ? 1.0f : 0.0f;
        const float vy0 = (y0f >= 0.0f && y0f <= (float)(H - 1)) ? 1.0f : 0.0f;
        const float vy1 = (y1f >= 0.0f && y1f <= (float)(H - 1)) ? 1.0f : 0.0f;
        const int x0 = min(max((int)x0f, 0), W - 1);
        const int x1 = min(max((int)x1f, 0), W - 1);
        const int y0 = min(max((int)y0f, 0), H - 1);
        const int y1 = min(max((int)y1f, 0), H - 1);
        const float* base = feats[L] + ((size_t)b * NCH + c) * (size_t)(H * W);
        const float acc = base[y0 * W + x0] * (wx0 * wy0 * vx0 * vy0)
                        + base[y0 * W + x1] * (wx1 * wy0 * vx1 * vy0)
                        + base[y1 * W + x0] * (wx0 * wy1 * vx0 * vy1)
                        + base[y1 * W + x1] * (wx1 * wy1 * vx1 * vy1);
        out[((size_t)n * 1024 + (size_t)L * NCH + c) * NPTS + p] = acc;
    }
}

extern "C" void kernel_launch(void* const* d_in, const int* in_sizes, int n_in,
                              void* d_out, int out_size, void* d_ws, size_t ws_size,
                              hipStream_t stream)
{
    const float* f0     = (const float*)d_in[0];
    const float* f1     = (const float*)d_in[1];
    const float* f2     = (const float*)d_in[2];
    const float* f3     = (const float*)d_in[3];
    const float* rois   = (const float*)d_in[4];
    const float* points = (const float*)d_in[5];
    float*       out    = (float*)d_out;

    const size_t WS_NEED = 45696000ull * 2ull;   // 91.4 MB bf16 HWC copy

    if (ws_size >= WS_NEED) {
        __hip_bfloat16* ws = (__hip_bfloat16*)d_ws;
        transpose_all<<<dim3(11168), 256, 0, stream>>>(f0, f1, f2, f3, ws);
        sample_all<<<dim3(NROI * 4), 256, 0, stream>>>(ws, rois, points, out);
    } else {
        mpe_kernel<<<dim3(NROI * NPTS), 256, 0, stream>>>(f0, f1, f2, f3, rois, points, out);
    }
}

// Round 10
// 159.179 us; speedup vs baseline: 12.8310x; 1.1115x over previous
//
#include <hip/hip_runtime.h>
#include <hip/hip_bf16.h>

#define NROI 1024
#define NPTS 49
#define NCH  256

// Level geometry:  L: 0      1     2     3
//                  H: 200    100   50    25
//                  W: 336    168   84    42
//                 HW: 67200  16800 4200  1050
// bf16 ws offsets (elements): t0=0, t1=34406400, t2=43008000, t3=45158400
// total 45,696,000 bf16 = 91.4 MB

__device__ __forceinline__ float bflo(unsigned u) { return __uint_as_float(u << 16); }
__device__ __forceinline__ float bfhi(unsigned u) { return __uint_as_float(u & 0xffff0000u); }

// ---------------- fused transpose: [B][C][HW] f32 -> [B][HW][C] bf16 ----------------
__global__ __launch_bounds__(256) void transpose_all(
    const float* __restrict__ f0, const float* __restrict__ f1,
    const float* __restrict__ f2, const float* __restrict__ f3,
    __hip_bfloat16* __restrict__ ws)
{
    int bid = blockIdx.x;
    const float* in;
    __hip_bfloat16* outp;
    int HW;
    if (bid < 8400)       { in = f0; outp = ws;            HW = 67200; }
    else if (bid < 10504) { bid -= 8400;  in = f1; outp = ws + 34406400; HW = 16800; }
    else if (bid < 11032) { bid -= 10504; in = f2; outp = ws + 43008000; HW = 4200;  }
    else                  { bid -= 11032; in = f3; outp = ws + 45158400; HW = 1050;  }
    const int hwc = bid >> 3;
    const int rem = bid & 7;
    const int c0  = (rem >> 1) * 64;
    const int b   = rem & 1;
    const int hw0 = hwc * 64;

    __shared__ float tile[64][65];
    const int tx = threadIdx.x & 63;
    const int ty = threadIdx.x >> 6;            // 0..3
    const float* ib       = in   + (size_t)b * NCH * HW;
    __hip_bfloat16* ob    = outp + (size_t)b * HW * NCH;

#pragma unroll
    for (int r = ty; r < 64; r += 4) {
        const int hw = hw0 + tx;
        if (hw < HW) tile[r][tx] = ib[(size_t)(c0 + r) * HW + hw];
    }
    __syncthreads();
#pragma unroll
    for (int r = ty; r < 64; r += 4) {
        const int hw = hw0 + r;
        if (hw < HW) ob[(size_t)hw * NCH + c0 + tx] = __float2bfloat16(tile[tx][r]);
    }
}

// ---------------- fused sample: all (roi, level, c-half) tuples ----------------
// block = (n, L, half); 256 threads = 16 channel-octets x 16 point-groups.
// Taps are 16 B uint4 (8 bf16 channels) -> 16 lanes cover 256 B contiguous.
// LDS 25088 B/block -> 6 blocks/CU -> 24 waves/CU for gather-latency hiding.
__global__ __launch_bounds__(256) void sample_all(
    const __hip_bfloat16* __restrict__ ws,
    const float* __restrict__ rois,
    const float* __restrict__ points,
    float* __restrict__ out)
{
    __shared__ __align__(16) float tile[128 * NPTS];   // 25088 B

    const int n    = blockIdx.x >> 3;
    const int rem  = blockIdx.x & 7;
    const int L    = rem >> 1;
    const int half = rem & 1;

    const __hip_bfloat16* ft;
    int H, W;
    float invS;
    if (L == 0)      { ft = ws;            H = 200; W = 336; invS = 0.25f;    }
    else if (L == 1) { ft = ws + 34406400; H = 100; W = 168; invS = 0.125f;   }
    else if (L == 2) { ft = ws + 43008000; H = 50;  W = 84;  invS = 0.0625f;  }
    else             { ft = ws + 45158400; H = 25;  W = 42;  invS = 0.03125f; }

    const int cl = (threadIdx.x & 15) * 8;       // local channel 0..120
    const int c  = half * 128 + cl;              // global channel
    const int pg = threadIdx.x >> 4;             // point group 0..15

    const float bi  = rois[n * 5 + 0];
    const float rx1 = rois[n * 5 + 1];
    const float ry1 = rois[n * 5 + 2];
    const float rx2 = rois[n * 5 + 3];
    const float ry2 = rois[n * 5 + 4];
    const int   b   = (int)bi;

    const unsigned short* fb =
        (const unsigned short*)(ft + (size_t)b * H * W * NCH);

    for (int p = pg; p < NPTS; p += 16) {
        const float px = points[((size_t)n * NPTS + p) * 2 + 0];
        const float py = points[((size_t)n * NPTS + p) * 2 + 1];
        const float cx = rx1 + px * (rx2 - rx1);
        const float cy = ry1 + py * (ry2 - ry1);

        // grid_sample align_corners=False collapses to coord/stride - 0.5
        const float x = cx * invS - 0.5f;
        const float y = cy * invS - 0.5f;

        const float x0f = floorf(x), y0f = floorf(y);
        const float wx1 = x - x0f, wx0 = 1.0f - wx1;
        const float wy1 = y - y0f, wy0 = 1.0f - wy1;
        const float x1f = x0f + 1.0f, y1f = y0f + 1.0f;

        const float vx0 = (x0f >= 0.0f && x0f <= (float)(W - 1)) ? 1.0f : 0.0f;
        const float vx1 = (x1f >= 0.0f && x1f <= (float)(W - 1)) ? 1.0f : 0.0f;
        const float vy0 = (y0f >= 0.0f && y0f <= (float)(H - 1)) ? 1.0f : 0.0f;
        const float vy1 = (y1f >= 0.0f && y1f <= (float)(H - 1)) ? 1.0f : 0.0f;

        const int x0 = min(max((int)x0f, 0), W - 1);
        const int x1 = min(max((int)x1f, 0), W - 1);
        const int y0 = min(max((int)y0f, 0), H - 1);
        const int y1 = min(max((int)y1f, 0), H - 1);

        const float w00 = wx0 * wy0 * vx0 * vy0;
        const float w01 = wx1 * wy0 * vx1 * vy0;
        const float w10 = wx0 * wy1 * vx0 * vy1;
        const float w11 = wx1 * wy1 * vx1 * vy1;

        const uint4 u00 = *(const uint4*)(fb + ((size_t)y0 * W + x0) * NCH + c);
        const uint4 u01 = *(const uint4*)(fb + ((size_t)y0 * W + x1) * NCH + c);
        const uint4 u10 = *(const uint4*)(fb + ((size_t)y1 * W + x0) * NCH + c);
        const uint4 u11 = *(const uint4*)(fb + ((size_t)y1 * W + x1) * NCH + c);

        float acc[8];
#pragma unroll
        for (int k = 0; k < 8; ++k) acc[k] = 0.0f;
#define ACCUM(UVEC, WGT) \
        acc[0] += bflo((UVEC).x) * (WGT); acc[1] += bfhi((UVEC).x) * (WGT); \
        acc[2] += bflo((UVEC).y) * (WGT); acc[3] += bfhi((UVEC).y) * (WGT); \
        acc[4] += bflo((UVEC).z) * (WGT); acc[5] += bfhi((UVEC).z) * (WGT); \
        acc[6] += bflo((UVEC).w) * (WGT); acc[7] += bfhi((UVEC).w) * (WGT);
        ACCUM(u00, w00)
        ACCUM(u01, w01)
        ACCUM(u10, w10)
        ACCUM(u11, w11)
#undef ACCUM

#pragma unroll
        for (int k = 0; k < 8; ++k)
            tile[(cl + k) * NPTS + p] = acc[k];
    }
    __syncthreads();

    // contiguous 25 KB write of the [128 x 49] half tile
    const float4* t4 = (const float4*)tile;
    float4* o4 = (float4*)(out + ((size_t)n * 1024 + (size_t)L * NCH + half * 128) * NPTS);
#pragma unroll 4
    for (int i = threadIdx.x; i < (128 * NPTS) / 4; i += 256)
        o4[i] = t4[i];
}

// ---------------- fallback: direct BCHW sampling (round-4 verified) ----------------
__global__ __launch_bounds__(256) void mpe_kernel(
    const float* __restrict__ f0, const float* __restrict__ f1,
    const float* __restrict__ f2, const float* __restrict__ f3,
    const float* __restrict__ rois, const float* __restrict__ points,
    float* __restrict__ out)
{
    const int np = blockIdx.x;
    const int n  = np / NPTS;
    const int p  = np - n * NPTS;
    const int c  = threadIdx.x;

    const float bi  = rois[n * 5 + 0];
    const float rx1 = rois[n * 5 + 1];
    const float ry1 = rois[n * 5 + 2];
    const float rx2 = rois[n * 5 + 3];
    const float ry2 = rois[n * 5 + 4];
    const int   b   = (int)bi;

    const float px = points[(size_t)np * 2 + 0];
    const float py = points[(size_t)np * 2 + 1];
    const float cx = rx1 + px * (rx2 - rx1);
    const float cy = ry1 + py * (ry2 - ry1);

    const float* feats[4] = {f0, f1, f2, f3};
    const int   Hs[4]   = {200, 100, 50, 25};
    const int   Ws[4]   = {336, 168, 84, 42};
    const float invS[4] = {0.25f, 0.125f, 0.0625f, 0.03125f};

#pragma unroll
    for (int L = 0; L < 4; ++L) {
        const int H = Hs[L], W = Ws[L];
        const float x = cx * invS[L] - 0.5f;
        const float y = cy * invS[L] - 0.5f;
        const float x0f = floorf(x), y0f = floorf(y);
        const float wx1 = x - x0f, wx0 = 1.0f - wx1;
        const float wy1 = y - y0f, wy0 = 1.0f - wy1;
        const float x1f = x0f + 1.0f, y1f = y0f + 1.0f;
        const float vx0 = (x0f >= 0.0f && x0f <= (float)(W - 1)) ? 1.0f : 0.0f;
        const float vx1 = (x1f >= 0.0f && x1f <= (float)(W - 1)) ? 1.0f : 0.0f;
        const float vy0 = (y0f >= 0.0f && y0f <= (float)(H - 1)) ? 1.0f : 0.0f;
        const float vy1 = (y1f >= 0.0f && y1f <= (float)(H - 1)) ? 1.0f : 0.0f;
        const int x0 = min(max((int)x0f, 0), W - 1);
        const int x1 = min(max((int)x1f, 0), W - 1);
        const int y0 = min(max((int)y0f, 0), H - 1);
        const int y1 = min(max((int)y1f, 0), H - 1);
        const float* base = feats[L] + ((size_t)b * NCH + c) * (size_t)(H * W);
        const float acc = base[y0 * W + x0] * (wx0 * wy0 * vx0 * vy0)
                        + base[y0 * W + x1] * (wx1 * wy0 * vx1 * vy0)
                        + base[y1 * W + x0] * (wx0 * wy1 * vx0 * vy1)
                        + base[y1 * W + x1] * (wx1 * wy1 * vx1 * vy1);
        out[((size_t)n * 1024 + (size_t)L * NCH + c) * NPTS + p] = acc;
    }
}

extern "C" void kernel_launch(void* const* d_in, const int* in_sizes, int n_in,
                              void* d_out, int out_size, void* d_ws, size_t ws_size,
                              hipStream_t stream)
{
    const float* f0     = (const float*)d_in[0];
    const float* f1     = (const float*)d_in[1];
    const float* f2     = (const float*)d_in[2];
    const float* f3     = (const float*)d_in[3];
    const float* rois   = (const float*)d_in[4];
    const float* points = (const float*)d_in[5];
    float*       out    = (float*)d_out;

    const size_t WS_NEED = 45696000ull * 2ull;   // 91.4 MB bf16 HWC copy

    if (ws_size >= WS_NEED) {
        __hip_bfloat16* ws = (__hip_bfloat16*)d_ws;
        transpose_all<<<dim3(11168), 256, 0, stream>>>(f0, f1, f2, f3, ws);
        sample_all<<<dim3(NROI * 8), 256, 0, stream>>>(ws, rois, points, out);
    } else {
        mpe_kernel<<<dim3(NROI * NPTS), 256, 0, stream>>>(f0, f1, f2, f3, rois, points, out);
    }
}

// Round 11
// 156.925 us; speedup vs baseline: 13.0154x; 1.0144x over previous
//
#include <hip/hip_runtime.h>
#include <hip/hip_bf16.h>

#define NROI 1024
#define NPTS 49
#define NCH  256

// Level geometry:  L: 0      1     2     3
//                  H: 200    100   50    25
//                  W: 336    168   84    42
//                 HW: 67200  16800 4200  1050
// bf16 ws offsets (elements): t0=0, t1=34406400, t2=43008000, t3=45158400
// total 45,696,000 bf16 = 91.4 MB

__device__ __forceinline__ float bflo(unsigned u) { return __uint_as_float(u << 16); }
__device__ __forceinline__ float bfhi(unsigned u) { return __uint_as_float(u & 0xffff0000u); }

// ---------------- fused transpose: [B][C][HW] f32 -> [B][HW][C] bf16 ----------------
__global__ __launch_bounds__(256) void transpose_all(
    const float* __restrict__ f0, const float* __restrict__ f1,
    const float* __restrict__ f2, const float* __restrict__ f3,
    __hip_bfloat16* __restrict__ ws)
{
    int bid = blockIdx.x;
    const float* in;
    __hip_bfloat16* outp;
    int HW;
    if (bid < 8400)       { in = f0; outp = ws;            HW = 67200; }
    else if (bid < 10504) { bid -= 8400;  in = f1; outp = ws + 34406400; HW = 16800; }
    else if (bid < 11032) { bid -= 10504; in = f2; outp = ws + 43008000; HW = 4200;  }
    else                  { bid -= 11032; in = f3; outp = ws + 45158400; HW = 1050;  }
    const int hwc = bid >> 3;
    const int rem = bid & 7;
    const int c0  = (rem >> 1) * 64;
    const int b   = rem & 1;
    const int hw0 = hwc * 64;

    __shared__ float tile[64][65];
    const int tx = threadIdx.x & 63;
    const int ty = threadIdx.x >> 6;            // 0..3
    const float* ib       = in   + (size_t)b * NCH * HW;
    __hip_bfloat16* ob    = outp + (size_t)b * HW * NCH;

#pragma unroll
    for (int r = ty; r < 64; r += 4) {
        const int hw = hw0 + tx;
        if (hw < HW) tile[r][tx] = ib[(size_t)(c0 + r) * HW + hw];
    }
    __syncthreads();
#pragma unroll
    for (int r = ty; r < 64; r += 4) {
        const int hw = hw0 + r;
        if (hw < HW) ob[(size_t)hw * NCH + c0 + tx] = __float2bfloat16(tile[tx][r]);
    }
}

// -------- per-point bilinear weight/offset computation (shared helper) --------
__device__ __forceinline__ void point_wo(
    float px, float py, float rx1, float ry1, float rx2, float ry2,
    float invS, int H, int W,
    float& w00, float& w01, float& w10, float& w11, unsigned& o00,
    unsigned& o01, unsigned& o10, unsigned& o11)
{
    const float cx = rx1 + px * (rx2 - rx1);
    const float cy = ry1 + py * (ry2 - ry1);
    // grid_sample align_corners=False collapses to coord/stride - 0.5
    const float x = cx * invS - 0.5f;
    const float y = cy * invS - 0.5f;

    const float x0f = floorf(x), y0f = floorf(y);
    const float wx1 = x - x0f, wx0 = 1.0f - wx1;
    const float wy1 = y - y0f, wy0 = 1.0f - wy1;
    const float x1f = x0f + 1.0f, y1f = y0f + 1.0f;

    const float vx0 = (x0f >= 0.0f && x0f <= (float)(W - 1)) ? 1.0f : 0.0f;
    const float vx1 = (x1f >= 0.0f && x1f <= (float)(W - 1)) ? 1.0f : 0.0f;
    const float vy0 = (y0f >= 0.0f && y0f <= (float)(H - 1)) ? 1.0f : 0.0f;
    const float vy1 = (y1f >= 0.0f && y1f <= (float)(H - 1)) ? 1.0f : 0.0f;

    const int x0 = min(max((int)x0f, 0), W - 1);
    const int x1 = min(max((int)x1f, 0), W - 1);
    const int y0 = min(max((int)y0f, 0), H - 1);
    const int y1 = min(max((int)y1f, 0), H - 1);

    w00 = wx0 * wy0 * vx0 * vy0;
    w01 = wx1 * wy0 * vx1 * vy0;
    w10 = wx0 * wy1 * vx0 * vy1;
    w11 = wx1 * wy1 * vx1 * vy1;

    o00 = ((unsigned)y0 * W + x0) * NCH;
    o01 = ((unsigned)y0 * W + x1) * NCH;
    o10 = ((unsigned)y1 * W + x0) * NCH;
    o11 = ((unsigned)y1 * W + x1) * NCH;
}

// ---------------- fused sample: all (roi, level, c-half) tuples ----------------
// block = (n, L, half); 256 threads = 16 channel-octets x 16 point-groups.
// Fully unrolled 3-points-per-thread (+ tail p=48 on pg==0): all 12 uint4 tap
// loads are issued back-to-back for memory-level parallelism (L3-hit latency
// was the round-10 limiter).
__global__ __launch_bounds__(256) void sample_all(
    const __hip_bfloat16* __restrict__ ws,
    const float* __restrict__ rois,
    const float* __restrict__ points,
    float* __restrict__ out)
{
    __shared__ __align__(16) float tile[128 * NPTS];   // 25088 B

    const int n    = blockIdx.x >> 3;
    const int rem  = blockIdx.x & 7;
    const int L    = rem >> 1;
    const int half = rem & 1;

    const __hip_bfloat16* ft;
    int H, W;
    float invS;
    if (L == 0)      { ft = ws;            H = 200; W = 336; invS = 0.25f;    }
    else if (L == 1) { ft = ws + 34406400; H = 100; W = 168; invS = 0.125f;   }
    else if (L == 2) { ft = ws + 43008000; H = 50;  W = 84;  invS = 0.0625f;  }
    else             { ft = ws + 45158400; H = 25;  W = 42;  invS = 0.03125f; }

    const int cl = (threadIdx.x & 15) * 8;       // local channel 0..120
    const int c  = half * 128 + cl;              // global channel
    const int pg = threadIdx.x >> 4;             // point group 0..15

    const float bi  = rois[n * 5 + 0];
    const float rx1 = rois[n * 5 + 1];
    const float ry1 = rois[n * 5 + 2];
    const float rx2 = rois[n * 5 + 3];
    const float ry2 = rois[n * 5 + 4];
    const int   b   = (int)bi;

    const unsigned short* fb =
        (const unsigned short*)(ft + (size_t)b * H * W * NCH);

    // ---- phase A: weights + offsets for all 3 points ----
    float w00[3], w01[3], w10[3], w11[3];
    unsigned o00[3], o01[3], o10[3], o11[3];
#pragma unroll
    for (int i = 0; i < 3; ++i) {
        const int p = pg + 16 * i;               // 49 = 3*16 + 1: p <= 47 here
        const float2 pt = *(const float2*)(points + ((size_t)n * NPTS + p) * 2);
        point_wo(pt.x, pt.y, rx1, ry1, rx2, ry2, invS, H, W,
                 w00[i], w01[i], w10[i], w11[i], o00[i], o01[i], o10[i], o11[i]);
    }

    // ---- phase B: issue all 12 tap loads back-to-back ----
    uint4 u00[3], u01[3], u10[3], u11[3];
#pragma unroll
    for (int i = 0; i < 3; ++i) {
        u00[i] = *(const uint4*)(fb + o00[i] + c);
        u01[i] = *(const uint4*)(fb + o01[i] + c);
        u10[i] = *(const uint4*)(fb + o10[i] + c);
        u11[i] = *(const uint4*)(fb + o11[i] + c);
    }

    // ---- phase C: FMA + LDS stores ----
#define ACCUM(UVEC, WGT) \
        acc[0] += bflo((UVEC).x) * (WGT); acc[1] += bfhi((UVEC).x) * (WGT); \
        acc[2] += bflo((UVEC).y) * (WGT); acc[3] += bfhi((UVEC).y) * (WGT); \
        acc[4] += bflo((UVEC).z) * (WGT); acc[5] += bfhi((UVEC).z) * (WGT); \
        acc[6] += bflo((UVEC).w) * (WGT); acc[7] += bfhi((UVEC).w) * (WGT);
#pragma unroll
    for (int i = 0; i < 3; ++i) {
        const int p = pg + 16 * i;
        float acc[8];
#pragma unroll
        for (int k = 0; k < 8; ++k) acc[k] = 0.0f;
        ACCUM(u00[i], w00[i])
        ACCUM(u01[i], w01[i])
        ACCUM(u10[i], w10[i])
        ACCUM(u11[i], w11[i])
#pragma unroll
        for (int k = 0; k < 8; ++k)
            tile[(cl + k) * NPTS + p] = acc[k];
    }

    // ---- tail point p = 48 (only channel-octet owners in group 0) ----
    if (pg == 0) {
        const float2 pt = *(const float2*)(points + ((size_t)n * NPTS + 48) * 2);
        float tw00, tw01, tw10, tw11;
        unsigned to00, to01, to10, to11;
        point_wo(pt.x, pt.y, rx1, ry1, rx2, ry2, invS, H, W,
                 tw00, tw01, tw10, tw11, to00, to01, to10, to11);
        const uint4 v00 = *(const uint4*)(fb + to00 + c);
        const uint4 v01 = *(const uint4*)(fb + to01 + c);
        const uint4 v10 = *(const uint4*)(fb + to10 + c);
        const uint4 v11 = *(const uint4*)(fb + to11 + c);
        float acc[8];
#pragma unroll
        for (int k = 0; k < 8; ++k) acc[k] = 0.0f;
        ACCUM(v00, tw00)
        ACCUM(v01, tw01)
        ACCUM(v10, tw10)
        ACCUM(v11, tw11)
#pragma unroll
        for (int k = 0; k < 8; ++k)
            tile[(cl + k) * NPTS + 48] = acc[k];
    }
#undef ACCUM
    __syncthreads();

    // contiguous 25 KB write of the [128 x 49] half tile
    const float4* t4 = (const float4*)tile;
    float4* o4 = (float4*)(out + ((size_t)n * 1024 + (size_t)L * NCH + half * 128) * NPTS);
#pragma unroll 4
    for (int i = threadIdx.x; i < (128 * NPTS) / 4; i += 256)
        o4[i] = t4[i];
}

// ---------------- fallback: direct BCHW sampling (round-4 verified) ----------------
__global__ __launch_bounds__(256) void mpe_kernel(
    const float* __restrict__ f0, const float* __restrict__ f1,
    const float* __restrict__ f2, const float* __restrict__ f3,
    const float* __restrict__ rois, const float* __restrict__ points,
    float* __restrict__ out)
{
    const int np = blockIdx.x;
    const int n  = np / NPTS;
    const int p  = np - n * NPTS;
    const int c  = threadIdx.x;

    const float bi  = rois[n * 5 + 0];
    const float rx1 = rois[n * 5 + 1];
    const float ry1 = rois[n * 5 + 2];
    const float rx2 = rois[n * 5 + 3];
    const float ry2 = rois[n * 5 + 4];
    const int   b   = (int)bi;

    const float px = points[(size_t)np * 2 + 0];
    const float py = points[(size_t)np * 2 + 1];
    const float cx = rx1 + px * (rx2 - rx1);
    const float cy = ry1 + py * (ry2 - ry1);

    const float* feats[4] = {f0, f1, f2, f3};
    const int   Hs[4]   = {200, 100, 50, 25};
    const int   Ws[4]   = {336, 168, 84, 42};
    const float invS[4] = {0.25f, 0.125f, 0.0625f, 0.03125f};

#pragma unroll
    for (int L = 0; L < 4; ++L) {
        const int H = Hs[L], W = Ws[L];
        const float x = cx * invS[L] - 0.5f;
        const float y = cy * invS[L] - 0.5f;
        const float x0f = floorf(x), y0f = floorf(y);
        const float wx1 = x - x0f, wx0 = 1.0f - wx1;
        const float wy1 = y - y0f, wy0 = 1.0f - wy1;
        const float x1f = x0f + 1.0f, y1f = y0f + 1.0f;
        const float vx0 = (x0f >= 0.0f && x0f <= (float)(W - 1)) ? 1.0f : 0.0f;
        const float vx1 = (x1f >= 0.0f && x1f <= (float)(W - 1)) ? 1.0f : 0.0f;
        const float vy0 = (y0f >= 0.0f && y0f <= (float)(H - 1)) ? 1.0f : 0.0f;
        const float vy1 = (y1f >= 0.0f && y1f <= (float)(H - 1)) ? 1.0f : 0.0f;
        const int x0 = min(max((int)x0f, 0), W - 1);
        const int x1 = min(max((int)x1f, 0), W - 1);
        const int y0 = min(max((int)y0f, 0), H - 1);
        const int y1 = min(max((int)y1f, 0), H - 1);
        const float* base = feats[L] + ((size_t)b * NCH + c) * (size_t)(H * W);
        const float acc = base[y0 * W + x0] * (wx0 * wy0 * vx0 * vy0)
                        + base[y0 * W + x1] * (wx1 * wy0 * vx1 * vy0)
                        + base[y1 * W + x0] * (wx0 * wy1 * vx0 * vy1)
                        + base[y1 * W + x1] * (wx1 * wy1 * vx1 * vy1);
        out[((size_t)n * 1024 + (size_t)L * NCH + c) * NPTS + p] = acc;
    }
}

extern "C" void kernel_launch(void* const* d_in, const int* in_sizes, int n_in,
                              void* d_out, int out_size, void* d_ws, size_t ws_size,
                              hipStream_t stream)
{
    const float* f0     = (const float*)d_in[0];
    const float* f1     = (const float*)d_in[1];
    const float* f2     = (const float*)d_in[2];
    const float* f3     = (const float*)d_in[3];
    const float* rois   = (const float*)d_in[4];
    const float* points = (const float*)d_in[5];
    float*       out    = (float*)d_out;

    const size_t WS_NEED = 45696000ull * 2ull;   // 91.4 MB bf16 HWC copy

    if (ws_size >= WS_NEED) {
        __hip_bfloat16* ws = (__hip_bfloat16*)d_ws;
        transpose_all<<<dim3(11168), 256, 0, stream>>>(f0, f1, f2, f3, ws);
        sample_all<<<dim3(NROI * 8), 256, 0, stream>>>(ws, rois, points, out);
    } else {
        mpe_kernel<<<dim3(NROI * NPTS), 256, 0, stream>>>(f0, f1, f2, f3, rois, points, out);
    }
}

// Round 12
// 155.321 us; speedup vs baseline: 13.1498x; 1.0103x over previous
//
#include <hip/hip_runtime.h>
#include <hip/hip_bf16.h>

#define NROI 1024
#define NPTS 49
#define NCH  256

// Level geometry:  L: 0      1     2     3
//                  H: 200    100   50    25
//                  W: 336    168   84    42
//                 HW: 67200  16800 4200  1050
// bf16 ws offsets (elements): t0=0, t1=34406400, t2=43008000, t3=45158400
// total 45,696,000 bf16 = 91.4 MB

__device__ __forceinline__ float bflo(unsigned u) { return __uint_as_float(u << 16); }
__device__ __forceinline__ float bfhi(unsigned u) { return __uint_as_float(u & 0xffff0000u); }

// ---------------- fused transpose: [B][C][HW] f32 -> [B][HW][C] bf16 ----------------
__global__ __launch_bounds__(256) void transpose_all(
    const float* __restrict__ f0, const float* __restrict__ f1,
    const float* __restrict__ f2, const float* __restrict__ f3,
    __hip_bfloat16* __restrict__ ws)
{
    int bid = blockIdx.x;
    const float* in;
    __hip_bfloat16* outp;
    int HW;
    if (bid < 8400)       { in = f0; outp = ws;            HW = 67200; }
    else if (bid < 10504) { bid -= 8400;  in = f1; outp = ws + 34406400; HW = 16800; }
    else if (bid < 11032) { bid -= 10504; in = f2; outp = ws + 43008000; HW = 4200;  }
    else                  { bid -= 11032; in = f3; outp = ws + 45158400; HW = 1050;  }
    const int hwc = bid >> 3;
    const int rem = bid & 7;
    const int c0  = (rem >> 1) * 64;
    const int b   = rem & 1;
    const int hw0 = hwc * 64;

    __shared__ float tile[64][65];
    const int tx = threadIdx.x & 63;
    const int ty = threadIdx.x >> 6;            // 0..3
    const float* ib       = in   + (size_t)b * NCH * HW;
    __hip_bfloat16* ob    = outp + (size_t)b * HW * NCH;

#pragma unroll
    for (int r = ty; r < 64; r += 4) {
        const int hw = hw0 + tx;
        if (hw < HW) tile[r][tx] = ib[(size_t)(c0 + r) * HW + hw];
    }
    __syncthreads();
#pragma unroll
    for (int r = ty; r < 64; r += 4) {
        const int hw = hw0 + r;
        if (hw < HW) ob[(size_t)hw * NCH + c0 + tx] = __float2bfloat16(tile[tx][r]);
    }
}

// -------- per-point bilinear weight/offset computation (shared helper) --------
__device__ __forceinline__ void point_wo(
    float px, float py, float rx1, float ry1, float rx2, float ry2,
    float invS, int H, int W,
    float& w00, float& w01, float& w10, float& w11, unsigned& o00,
    unsigned& o01, unsigned& o10, unsigned& o11)
{
    const float cx = rx1 + px * (rx2 - rx1);
    const float cy = ry1 + py * (ry2 - ry1);
    // grid_sample align_corners=False collapses to coord/stride - 0.5
    const float x = cx * invS - 0.5f;
    const float y = cy * invS - 0.5f;

    const float x0f = floorf(x), y0f = floorf(y);
    const float wx1 = x - x0f, wx0 = 1.0f - wx1;
    const float wy1 = y - y0f, wy0 = 1.0f - wy1;
    const float x1f = x0f + 1.0f, y1f = y0f + 1.0f;

    const float vx0 = (x0f >= 0.0f && x0f <= (float)(W - 1)) ? 1.0f : 0.0f;
    const float vx1 = (x1f >= 0.0f && x1f <= (float)(W - 1)) ? 1.0f : 0.0f;
    const float vy0 = (y0f >= 0.0f && y0f <= (float)(H - 1)) ? 1.0f : 0.0f;
    const float vy1 = (y1f >= 0.0f && y1f <= (float)(H - 1)) ? 1.0f : 0.0f;

    const int x0 = min(max((int)x0f, 0), W - 1);
    const int x1 = min(max((int)x1f, 0), W - 1);
    const int y0 = min(max((int)y0f, 0), H - 1);
    const int y1 = min(max((int)y1f, 0), H - 1);

    w00 = wx0 * wy0 * vx0 * vy0;
    w01 = wx1 * wy0 * vx1 * vy0;
    w10 = wx0 * wy1 * vx0 * vy1;
    w11 = wx1 * wy1 * vx1 * vy1;

    o00 = ((unsigned)y0 * W + x0) * NCH;
    o01 = ((unsigned)y0 * W + x1) * NCH;
    o10 = ((unsigned)y1 * W + x0) * NCH;
    o11 = ((unsigned)y1 * W + x1) * NCH;
}

// ---------------- fused sample: all (roi, level, c-half) tuples ----------------
// block = (n, L, half); 256 threads = 16 channel-octets x 16 point-groups.
// XCD balance: dispatch assigns XCD = blockIdx.x % 8. Without rotation,
// (L,half) is statically pinned to an XCD, so the two XCDs serving level-0
// halves (34.4 MB L3-only slices) are ~5x slower than the XCDs serving the
// L2-resident level-2/3 slices, and they gate the kernel. Rotating the
// (L,half) code per-roi gives every XCD an equal mix of levels.
__global__ __launch_bounds__(256) void sample_all(
    const __hip_bfloat16* __restrict__ ws,
    const float* __restrict__ rois,
    const float* __restrict__ points,
    float* __restrict__ out)
{
    __shared__ __align__(16) float tile[128 * NPTS];   // 25088 B

    const int bid  = blockIdx.x;
    const int n    = bid >> 3;
    const int rem  = ((bid & 7) + n) & 7;        // per-roi rotated (bijective)
    const int L    = rem >> 1;
    const int half = rem & 1;

    const __hip_bfloat16* ft;
    int H, W;
    float invS;
    if (L == 0)      { ft = ws;            H = 200; W = 336; invS = 0.25f;    }
    else if (L == 1) { ft = ws + 34406400; H = 100; W = 168; invS = 0.125f;   }
    else if (L == 2) { ft = ws + 43008000; H = 50;  W = 84;  invS = 0.0625f;  }
    else             { ft = ws + 45158400; H = 25;  W = 42;  invS = 0.03125f; }

    const int cl = (threadIdx.x & 15) * 8;       // local channel 0..120
    const int c  = half * 128 + cl;              // global channel
    const int pg = threadIdx.x >> 4;             // point group 0..15

    const float bi  = rois[n * 5 + 0];
    const float rx1 = rois[n * 5 + 1];
    const float ry1 = rois[n * 5 + 2];
    const float rx2 = rois[n * 5 + 3];
    const float ry2 = rois[n * 5 + 4];
    const int   b   = (int)bi;

    const unsigned short* fb =
        (const unsigned short*)(ft + (size_t)b * H * W * NCH);

    // ---- phase A: weights + offsets for all 3 points ----
    float w00[3], w01[3], w10[3], w11[3];
    unsigned o00[3], o01[3], o10[3], o11[3];
#pragma unroll
    for (int i = 0; i < 3; ++i) {
        const int p = pg + 16 * i;               // 49 = 3*16 + 1: p <= 47 here
        const float2 pt = *(const float2*)(points + ((size_t)n * NPTS + p) * 2);
        point_wo(pt.x, pt.y, rx1, ry1, rx2, ry2, invS, H, W,
                 w00[i], w01[i], w10[i], w11[i], o00[i], o01[i], o10[i], o11[i]);
    }

    // ---- phase B: issue all 12 tap loads back-to-back ----
    uint4 u00[3], u01[3], u10[3], u11[3];
#pragma unroll
    for (int i = 0; i < 3; ++i) {
        u00[i] = *(const uint4*)(fb + o00[i] + c);
        u01[i] = *(const uint4*)(fb + o01[i] + c);
        u10[i] = *(const uint4*)(fb + o10[i] + c);
        u11[i] = *(const uint4*)(fb + o11[i] + c);
    }

    // ---- phase C: FMA + LDS stores ----
#define ACCUM(UVEC, WGT) \
        acc[0] += bflo((UVEC).x) * (WGT); acc[1] += bfhi((UVEC).x) * (WGT); \
        acc[2] += bflo((UVEC).y) * (WGT); acc[3] += bfhi((UVEC).y) * (WGT); \
        acc[4] += bflo((UVEC).z) * (WGT); acc[5] += bfhi((UVEC).z) * (WGT); \
        acc[6] += bflo((UVEC).w) * (WGT); acc[7] += bfhi((UVEC).w) * (WGT);
#pragma unroll
    for (int i = 0; i < 3; ++i) {
        const int p = pg + 16 * i;
        float acc[8];
#pragma unroll
        for (int k = 0; k < 8; ++k) acc[k] = 0.0f;
        ACCUM(u00[i], w00[i])
        ACCUM(u01[i], w01[i])
        ACCUM(u10[i], w10[i])
        ACCUM(u11[i], w11[i])
#pragma unroll
        for (int k = 0; k < 8; ++k)
            tile[(cl + k) * NPTS + p] = acc[k];
    }

    // ---- tail point p = 48 (only channel-octet owners in group 0) ----
    if (pg == 0) {
        const float2 pt = *(const float2*)(points + ((size_t)n * NPTS + 48) * 2);
        float tw00, tw01, tw10, tw11;
        unsigned to00, to01, to10, to11;
        point_wo(pt.x, pt.y, rx1, ry1, rx2, ry2, invS, H, W,
                 tw00, tw01, tw10, tw11, to00, to01, to10, to11);
        const uint4 v00 = *(const uint4*)(fb + to00 + c);
        const uint4 v01 = *(const uint4*)(fb + to01 + c);
        const uint4 v10 = *(const uint4*)(fb + to10 + c);
        const uint4 v11 = *(const uint4*)(fb + to11 + c);
        float acc[8];
#pragma unroll
        for (int k = 0; k < 8; ++k) acc[k] = 0.0f;
        ACCUM(v00, tw00)
        ACCUM(v01, tw01)
        ACCUM(v10, tw10)
        ACCUM(v11, tw11)
#pragma unroll
        for (int k = 0; k < 8; ++k)
            tile[(cl + k) * NPTS + 48] = acc[k];
    }
#undef ACCUM
    __syncthreads();

    // contiguous 25 KB write of the [128 x 49] half tile
    const float4* t4 = (const float4*)tile;
    float4* o4 = (float4*)(out + ((size_t)n * 1024 + (size_t)L * NCH + half * 128) * NPTS);
#pragma unroll 4
    for (int i = threadIdx.x; i < (128 * NPTS) / 4; i += 256)
        o4[i] = t4[i];
}

// ---------------- fallback: direct BCHW sampling (round-4 verified) ----------------
__global__ __launch_bounds__(256) void mpe_kernel(
    const float* __restrict__ f0, const float* __restrict__ f1,
    const float* __restrict__ f2, const float* __restrict__ f3,
    const float* __restrict__ rois, const float* __restrict__ points,
    float* __restrict__ out)
{
    const int np = blockIdx.x;
    const int n  = np / NPTS;
    const int p  = np - n * NPTS;
    const int c  = threadIdx.x;

    const float bi  = rois[n * 5 + 0];
    const float rx1 = rois[n * 5 + 1];
    const float ry1 = rois[n * 5 + 2];
    const float rx2 = rois[n * 5 + 3];
    const float ry2 = rois[n * 5 + 4];
    const int   b   = (int)bi;

    const float px = points[(size_t)np * 2 + 0];
    const float py = points[(size_t)np * 2 + 1];
    const float cx = rx1 + px * (rx2 - rx1);
    const float cy = ry1 + py * (ry2 - ry1);

    const float* feats[4] = {f0, f1, f2, f3};
    const int   Hs[4]   = {200, 100, 50, 25};
    const int   Ws[4]   = {336, 168, 84, 42};
    const float invS[4] = {0.25f, 0.125f, 0.0625f, 0.03125f};

#pragma unroll
    for (int L = 0; L < 4; ++L) {
        const int H = Hs[L], W = Ws[L];
        const float x = cx * invS[L] - 0.5f;
        const float y = cy * invS[L] - 0.5f;
        const float x0f = floorf(x), y0f = floorf(y);
        const float wx1 = x - x0f, wx0 = 1.0f - wx1;
        const float wy1 = y - y0f, wy0 = 1.0f - wy1;
        const float x1f = x0f + 1.0f, y1f = y0f + 1.0f;
        const float vx0 = (x0f >= 0.0f && x0f <= (float)(W - 1)) ? 1.0f : 0.0f;
        const float vx1 = (x1f >= 0.0f && x1f <= (float)(W - 1)) ? 1.0f : 0.0f;
        const float vy0 = (y0f >= 0.0f && y0f <= (float)(H - 1)) ? 1.0f : 0.0f;
        const float vy1 = (y1f >= 0.0f && y1f <= (float)(H - 1)) ? 1.0f : 0.0f;
        const int x0 = min(max((int)x0f, 0), W - 1);
        const int x1 = min(max((int)x1f, 0), W - 1);
        const int y0 = min(max((int)y0f, 0), H - 1);
        const int y1 = min(max((int)y1f, 0), H - 1);
        const float* base = feats[L] + ((size_t)b * NCH + c) * (size_t)(H * W);
        const float acc = base[y0 * W + x0] * (wx0 * wy0 * vx0 * vy0)
                        + base[y0 * W + x1] * (wx1 * wy0 * vx1 * vy0)
                        + base[y1 * W + x0] * (wx0 * wy1 * vx0 * vy1)
                        + base[y1 * W + x1] * (wx1 * wy1 * vx1 * vy1);
        out[((size_t)n * 1024 + (size_t)L * NCH + c) * NPTS + p] = acc;
    }
}

extern "C" void kernel_launch(void* const* d_in, const int* in_sizes, int n_in,
                              void* d_out, int out_size, void* d_ws, size_t ws_size,
                              hipStream_t stream)
{
    const float* f0     = (const float*)d_in[0];
    const float* f1     = (const float*)d_in[1];
    const float* f2     = (const float*)d_in[2];
    const float* f3     = (const float*)d_in[3];
    const float* rois   = (const float*)d_in[4];
    const float* points = (const float*)d_in[5];
    float*       out    = (float*)d_out;

    const size_t WS_NEED = 45696000ull * 2ull;   // 91.4 MB bf16 HWC copy

    if (ws_size >= WS_NEED) {
        __hip_bfloat16* ws = (__hip_bfloat16*)d_ws;
        transpose_all<<<dim3(11168), 256, 0, stream>>>(f0, f1, f2, f3, ws);
        sample_all<<<dim3(NROI * 8), 256, 0, stream>>>(ws, rois, points, out);
    } else {
        mpe_kernel<<<dim3(NROI * NPTS), 256, 0, stream>>>(f0, f1, f2, f3, rois, points, out);
    }
}

// Round 15
// 151.944 us; speedup vs baseline: 13.4420x; 1.0222x over previous
//
#include <hip/hip_runtime.h>
#include <hip/hip_bf16.h>

#define NROI 1024
#define NPTS 49
#define NCH  256

// Level geometry:  L: 0      1     2     3
//                  H: 200    100   50    25
//                  W: 336    168   84    42
//                 HW: 67200  16800 4200  1050
// bf16 ws offsets (elements): t0=0, t1=34406400, t2=43008000, t3=45158400
// total 45,696,000 bf16 = 91.4 MB

typedef unsigned uintv4 __attribute__((ext_vector_type(4)));
typedef float    floatv4 __attribute__((ext_vector_type(4)));

__device__ __forceinline__ float bflo(unsigned u) { return __uint_as_float(u << 16); }
__device__ __forceinline__ float bfhi(unsigned u) { return __uint_as_float(u & 0xffff0000u); }

// ---------------- fused transpose: [B][C][HW] f32 -> [B][HW][C] bf16 ----------------
// Reads: nontemporal (read-once). Stores: 8 bf16 packed per lane (16 B, nontemporal).
__global__ __launch_bounds__(256) void transpose_all(
    const float* __restrict__ f0, const float* __restrict__ f1,
    const float* __restrict__ f2, const float* __restrict__ f3,
    __hip_bfloat16* __restrict__ ws)
{
    int bid = blockIdx.x;
    const float* in;
    __hip_bfloat16* outp;
    int HW;
    if (bid < 8400)       { in = f0; outp = ws;            HW = 67200; }
    else if (bid < 10504) { bid -= 8400;  in = f1; outp = ws + 34406400; HW = 16800; }
    else if (bid < 11032) { bid -= 10504; in = f2; outp = ws + 43008000; HW = 4200;  }
    else                  { bid -= 11032; in = f3; outp = ws + 45158400; HW = 1050;  }
    const int hwc = bid >> 3;
    const int rem = bid & 7;
    const int c0  = (rem >> 1) * 64;
    const int b   = rem & 1;
    const int hw0 = hwc * 64;

    __shared__ float tile[64][65];
    const int tx = threadIdx.x & 63;
    const int ty = threadIdx.x >> 6;            // 0..3
    const float* ib       = in   + (size_t)b * NCH * HW;
    __hip_bfloat16* ob    = outp + (size_t)b * HW * NCH;

#pragma unroll
    for (int r = ty; r < 64; r += 4) {
        const int hw = hw0 + tx;
        if (hw < HW) tile[r][tx] = __builtin_nontemporal_load(&ib[(size_t)(c0 + r) * HW + hw]);
    }
    __syncthreads();

    // store: lane -> (c-octet, hw row); pack 8 bf16 -> 16 B per lane
    const int oct = threadIdx.x & 7;            // which 8-channel group
    const int hwi = threadIdx.x >> 3;           // 0..31
#pragma unroll
    for (int s = 0; s < 2; ++s) {
        const int hwr = hwi + 32 * s;
        const int hw  = hw0 + hwr;
        if (hw < HW) {
            uintv4 pk;
#pragma unroll
            for (int j = 0; j < 4; ++j) {
                const unsigned lo = __float_as_uint(tile[oct * 8 + 2 * j + 0][hwr]);
                const unsigned hi = __float_as_uint(tile[oct * 8 + 2 * j + 1][hwr]);
                // round-to-nearest-even bf16 of two f32, packed
                const unsigned rlo = (lo + 0x7fffu + ((lo >> 16) & 1)) >> 16;
                const unsigned rhi = (hi + 0x7fffu + ((hi >> 16) & 1)) & 0xffff0000u;
                pk[j] = (rlo & 0xffffu) | rhi;
            }
            __builtin_nontemporal_store(pk,
                (uintv4*)((unsigned short*)ob + (size_t)hw * NCH + c0 + oct * 8));
        }
    }
}

// -------- per-point bilinear weight/offset computation (shared helper) --------
__device__ __forceinline__ void point_wo(
    float px, float py, float rx1, float ry1, float rx2, float ry2,
    float invS, int H, int W,
    float& w00, float& w01, float& w10, float& w11, unsigned& o00,
    unsigned& o01, unsigned& o10, unsigned& o11)
{
    const float cx = rx1 + px * (rx2 - rx1);
    const float cy = ry1 + py * (ry2 - ry1);
    // grid_sample align_corners=False collapses to coord/stride - 0.5
    const float x = cx * invS - 0.5f;
    const float y = cy * invS - 0.5f;

    const float x0f = floorf(x), y0f = floorf(y);
    const float wx1 = x - x0f, wx0 = 1.0f - wx1;
    const float wy1 = y - y0f, wy0 = 1.0f - wy1;
    const float x1f = x0f + 1.0f, y1f = y0f + 1.0f;

    const float vx0 = (x0f >= 0.0f && x0f <= (float)(W - 1)) ? 1.0f : 0.0f;
    const float vx1 = (x1f >= 0.0f && x1f <= (float)(W - 1)) ? 1.0f : 0.0f;
    const float vy0 = (y0f >= 0.0f && y0f <= (float)(H - 1)) ? 1.0f : 0.0f;
    const float vy1 = (y1f >= 0.0f && y1f <= (float)(H - 1)) ? 1.0f : 0.0f;

    const int x0 = min(max((int)x0f, 0), W - 1);
    const int x1 = min(max((int)x1f, 0), W - 1);
    const int y0 = min(max((int)y0f, 0), H - 1);
    const int y1 = min(max((int)y1f, 0), H - 1);

    w00 = wx0 * wy0 * vx0 * vy0;
    w01 = wx1 * wy0 * vx1 * vy0;
    w10 = wx0 * wy1 * vx0 * vy1;
    w11 = wx1 * wy1 * vx1 * vy1;

    o00 = ((unsigned)y0 * W + x0) * NCH;
    o01 = ((unsigned)y0 * W + x1) * NCH;
    o10 = ((unsigned)y1 * W + x0) * NCH;
    o11 = ((unsigned)y1 * W + x1) * NCH;
}

// ---------------- fused sample: all (roi, level, c-half) tuples ----------------
// block = (n, L, half); 256 threads = 16 channel-octets x 16 point-groups.
// Out stores are nontemporal (write-once) so the 205 MB stream doesn't evict
// the ws tap working set from L2.
__global__ __launch_bounds__(256) void sample_all(
    const __hip_bfloat16* __restrict__ ws,
    const float* __restrict__ rois,
    const float* __restrict__ points,
    float* __restrict__ out)
{
    __shared__ __align__(16) float tile[128 * NPTS];   // 25088 B

    const int bid  = blockIdx.x;
    const int n    = bid >> 3;
    const int rem  = ((bid & 7) + n) & 7;        // per-roi rotated (bijective)
    const int L    = rem >> 1;
    const int half = rem & 1;

    const __hip_bfloat16* ft;
    int H, W;
    float invS;
    if (L == 0)      { ft = ws;            H = 200; W = 336; invS = 0.25f;    }
    else if (L == 1) { ft = ws + 34406400; H = 100; W = 168; invS = 0.125f;   }
    else if (L == 2) { ft = ws + 43008000; H = 50;  W = 84;  invS = 0.0625f;  }
    else             { ft = ws + 45158400; H = 25;  W = 42;  invS = 0.03125f; }

    const int cl = (threadIdx.x & 15) * 8;       // local channel 0..120
    const int c  = half * 128 + cl;              // global channel
    const int pg = threadIdx.x >> 4;             // point group 0..15

    const float bi  = rois[n * 5 + 0];
    const float rx1 = rois[n * 5 + 1];
    const float ry1 = rois[n * 5 + 2];
    const float rx2 = rois[n * 5 + 3];
    const float ry2 = rois[n * 5 + 4];
    const int   b   = (int)bi;

    const unsigned short* fb =
        (const unsigned short*)(ft + (size_t)b * H * W * NCH);

    // ---- phase A: weights + offsets for all 3 points ----
    float w00[3], w01[3], w10[3], w11[3];
    unsigned o00[3], o01[3], o10[3], o11[3];
#pragma unroll
    for (int i = 0; i < 3; ++i) {
        const int p = pg + 16 * i;               // 49 = 3*16 + 1: p <= 47 here
        const float2 pt = *(const float2*)(points + ((size_t)n * NPTS + p) * 2);
        point_wo(pt.x, pt.y, rx1, ry1, rx2, ry2, invS, H, W,
                 w00[i], w01[i], w10[i], w11[i], o00[i], o01[i], o10[i], o11[i]);
    }

    // ---- phase B: issue all 12 tap loads back-to-back ----
    uint4 u00[3], u01[3], u10[3], u11[3];
#pragma unroll
    for (int i = 0; i < 3; ++i) {
        u00[i] = *(const uint4*)(fb + o00[i] + c);
        u01[i] = *(const uint4*)(fb + o01[i] + c);
        u10[i] = *(const uint4*)(fb + o10[i] + c);
        u11[i] = *(const uint4*)(fb + o11[i] + c);
    }

    // ---- phase C: FMA + LDS stores ----
#define ACCUM(UVEC, WGT) \
        acc[0] += bflo((UVEC).x) * (WGT); acc[1] += bfhi((UVEC).x) * (WGT); \
        acc[2] += bflo((UVEC).y) * (WGT); acc[3] += bfhi((UVEC).y) * (WGT); \
        acc[4] += bflo((UVEC).z) * (WGT); acc[5] += bfhi((UVEC).z) * (WGT); \
        acc[6] += bflo((UVEC).w) * (WGT); acc[7] += bfhi((UVEC).w) * (WGT);
#pragma unroll
    for (int i = 0; i < 3; ++i) {
        const int p = pg + 16 * i;
        float acc[8];
#pragma unroll
        for (int k = 0; k < 8; ++k) acc[k] = 0.0f;
        ACCUM(u00[i], w00[i])
        ACCUM(u01[i], w01[i])
        ACCUM(u10[i], w10[i])
        ACCUM(u11[i], w11[i])
#pragma unroll
        for (int k = 0; k < 8; ++k)
            tile[(cl + k) * NPTS + p] = acc[k];
    }

    // ---- tail point p = 48 (only channel-octet owners in group 0) ----
    if (pg == 0) {
        const float2 pt = *(const float2*)(points + ((size_t)n * NPTS + 48) * 2);
        float tw00, tw01, tw10, tw11;
        unsigned to00, to01, to10, to11;
        point_wo(pt.x, pt.y, rx1, ry1, rx2, ry2, invS, H, W,
                 tw00, tw01, tw10, tw11, to00, to01, to10, to11);
        const uint4 v00 = *(const uint4*)(fb + to00 + c);
        const uint4 v01 = *(const uint4*)(fb + to01 + c);
        const uint4 v10 = *(const uint4*)(fb + to10 + c);
        const uint4 v11 = *(const uint4*)(fb + to11 + c);
        float acc[8];
#pragma unroll
        for (int k = 0; k < 8; ++k) acc[k] = 0.0f;
        ACCUM(v00, tw00)
        ACCUM(v01, tw01)
        ACCUM(v10, tw10)
        ACCUM(v11, tw11)
#pragma unroll
        for (int k = 0; k < 8; ++k)
            tile[(cl + k) * NPTS + 48] = acc[k];
    }
#undef ACCUM
    __syncthreads();

    // contiguous 25 KB nontemporal write of the [128 x 49] half tile
    const floatv4* t4 = (const floatv4*)tile;
    floatv4* o4 = (floatv4*)(out + ((size_t)n * 1024 + (size_t)L * NCH + half * 128) * NPTS);
#pragma unroll 4
    for (int i = threadIdx.x; i < (128 * NPTS) / 4; i += 256)
        __builtin_nontemporal_store(t4[i], &o4[i]);
}

// ---------------- fallback: direct BCHW sampling (round-4 verified) ----------------
__global__ __launch_bounds__(256) void mpe_kernel(
    const float* __restrict__ f0, const float* __restrict__ f1,
    const float* __restrict__ f2, const float* __restrict__ f3,
    const float* __restrict__ rois, const float* __restrict__ points,
    float* __restrict__ out)
{
    const int np = blockIdx.x;
    const int n  = np / NPTS;
    const int p  = np - n * NPTS;
    const int c  = threadIdx.x;

    const float bi  = rois[n * 5 + 0];
    const float rx1 = rois[n * 5 + 1];
    const float ry1 = rois[n * 5 + 2];
    const float rx2 = rois[n * 5 + 3];
    const float ry2 = rois[n * 5 + 4];
    const int   b   = (int)bi;

    const float px = points[(size_t)np * 2 + 0];
    const float py = points[(size_t)np * 2 + 1];
    const float cx = rx1 + px * (rx2 - rx1);
    const float cy = ry1 + py * (ry2 - ry1);

    const float* feats[4] = {f0, f1, f2, f3};
    const int   Hs[4]   = {200, 100, 50, 25};
    const int   Ws[4]   = {336, 168, 84, 42};
    const float invS[4] = {0.25f, 0.125f, 0.0625f, 0.03125f};

#pragma unroll
    for (int L = 0; L < 4; ++L) {
        const int H = Hs[L], W = Ws[L];
        const float x = cx * invS[L] - 0.5f;
        const float y = cy * invS[L] - 0.5f;
        const float x0f = floorf(x), y0f = floorf(y);
        const float wx1 = x - x0f, wx0 = 1.0f - wx1;
        const float wy1 = y - y0f, wy0 = 1.0f - wy1;
        const float x1f = x0f + 1.0f, y1f = y0f + 1.0f;
        const float vx0 = (x0f >= 0.0f && x0f <= (float)(W - 1)) ? 1.0f : 0.0f;
        const float vx1 = (x1f >= 0.0f && x1f <= (float)(W - 1)) ? 1.0f : 0.0f;
        const float vy0 = (y0f >= 0.0f && y0f <= (float)(H - 1)) ? 1.0f : 0.0f;
        const float vy1 = (y1f >= 0.0f && y1f <= (float)(H - 1)) ? 1.0f : 0.0f;
        const int x0 = min(max((int)x0f, 0), W - 1);
        const int x1 = min(max((int)x1f, 0), W - 1);
        const int y0 = min(max((int)y0f, 0), H - 1);
        const int y1 = min(max((int)y1f, 0), H - 1);
        const float* base = feats[L] + ((size_t)b * NCH + c) * (size_t)(H * W);
        const float acc = base[y0 * W + x0] * (wx0 * wy0 * vx0 * vy0)
                        + base[y0 * W + x1] * (wx1 * wy0 * vx1 * vy0)
                        + base[y1 * W + x0] * (wx0 * wy1 * vx0 * vy1)
                        + base[y1 * W + x1] * (wx1 * wy1 * vx1 * vy1);
        out[((size_t)n * 1024 + (size_t)L * NCH + c) * NPTS + p] = acc;
    }
}

extern "C" void kernel_launch(void* const* d_in, const int* in_sizes, int n_in,
                              void* d_out, int out_size, void* d_ws, size_t ws_size,
                              hipStream_t stream)
{
    const float* f0     = (const float*)d_in[0];
    const float* f1     = (const float*)d_in[1];
    const float* f2     = (const float*)d_in[2];
    const float* f3     = (const float*)d_in[3];
    const float* rois   = (const float*)d_in[4];
    const float* points = (const float*)d_in[5];
    float*       out    = (float*)d_out;

    const size_t WS_NEED = 45696000ull * 2ull;   // 91.4 MB bf16 HWC copy

    if (ws_size >= WS_NEED) {
        __hip_bfloat16* ws = (__hip_bfloat16*)d_ws;
        transpose_all<<<dim3(11168), 256, 0, stream>>>(f0, f1, f2, f3, ws);
        sample_all<<<dim3(NROI * 8), 256, 0, stream>>>(ws, rois, points, out);
    } else {
        mpe_kernel<<<dim3(NROI * NPTS), 256, 0, stream>>>(f0, f1, f2, f3, rois, points, out);
    }
}

// Round 16
// 135.852 us; speedup vs baseline: 15.0343x; 1.1185x over previous
//
#include <hip/hip_runtime.h>
#include <hip/hip_bf16.h>

#define NROI 1024
#define NPTS 49
#define NCH  256

// Level geometry:  L: 0      1     2     3
//                  H: 200    100   50    25
//                  W: 336    168   84    42
//                 HW: 67200  16800 4200  1050
// bf16 ws offsets (elements): t0=0, t1=34406400, t2=43008000, t3=45158400
// total 45,696,000 bf16 = 91.4 MB

typedef unsigned uintv4 __attribute__((ext_vector_type(4)));
typedef float    floatv4 __attribute__((ext_vector_type(4)));

__device__ __forceinline__ float bflo(unsigned u) { return __uint_as_float(u << 16); }
__device__ __forceinline__ float bfhi(unsigned u) { return __uint_as_float(u & 0xffff0000u); }

// ---------------- fused transpose: [B][C][HW] f32 -> [B][HW][C] bf16 ----------------
// 64c x 128hw tiles: reads are float4/lane -> 512 B contiguous segments (2x the
// old 64x64 tiling); LDS f32 [64][129] is the classic conflict-free transpose pad.
// Blocks: L0 525*8=4200 | L1 132*8=1056 | L2 33*8=264 | L3 9*8=72 -> 5592 total.
__global__ __launch_bounds__(256) void transpose_all(
    const float* __restrict__ f0, const float* __restrict__ f1,
    const float* __restrict__ f2, const float* __restrict__ f3,
    __hip_bfloat16* __restrict__ ws)
{
    int bid = blockIdx.x;
    const float* in;
    __hip_bfloat16* outp;
    int HW;
    if (bid < 4200)      { in = f0; outp = ws;            HW = 67200; }
    else if (bid < 5256) { bid -= 4200; in = f1; outp = ws + 34406400; HW = 16800; }
    else if (bid < 5520) { bid -= 5256; in = f2; outp = ws + 43008000; HW = 4200;  }
    else                 { bid -= 5520; in = f3; outp = ws + 45158400; HW = 1050;  }
    const int tile_i = bid >> 3;
    const int rem    = bid & 7;
    const int c0     = (rem >> 1) * 64;
    const int b      = rem & 1;
    const int hw0    = tile_i * 128;

    __shared__ float tile[64][129];
    const float* ib    = in   + (size_t)b * NCH * HW;
    __hip_bfloat16* ob = outp + (size_t)b * HW * NCH;

    // ---- read phase: 8 c-rows per iteration, 32 lanes x float4 = 512 B/row ----
    const int lane32 = threadIdx.x & 31;
    const int rowq   = threadIdx.x >> 5;          // 0..7
    const int hwb    = lane32 * 4;
    const bool alig  = (HW % 4) == 0;             // L3 (1050) rows are 8B-offset
#pragma unroll
    for (int it = 0; it < 8; ++it) {
        const int r  = rowq + 8 * it;             // c row 0..63
        const int hw = hw0 + hwb;
        const float* src = &ib[(size_t)(c0 + r) * HW + hw];
        if (alig && hw + 4 <= HW) {
            floatv4 v = __builtin_nontemporal_load((const floatv4*)src);
            tile[r][hwb + 0] = v.x;
            tile[r][hwb + 1] = v.y;
            tile[r][hwb + 2] = v.z;
            tile[r][hwb + 3] = v.w;
        } else {
#pragma unroll
            for (int j = 0; j < 4; ++j)
                tile[r][hwb + j] = (hw + j < HW) ? src[j] : 0.0f;
        }
    }
    __syncthreads();

    // ---- write phase: pack 8 bf16 -> 16 B per lane; 8 lanes = 128 B per hw ----
    const int oct = threadIdx.x & 7;              // 8-channel group
    const int hwq = threadIdx.x >> 3;             // 0..31
#pragma unroll
    for (int s = 0; s < 4; ++s) {
        const int hwl = hwq + 32 * s;             // 0..127
        const int hw  = hw0 + hwl;
        if (hw < HW) {
            uintv4 pk;
#pragma unroll
            for (int j = 0; j < 4; ++j) {
                const unsigned lo = __float_as_uint(tile[oct * 8 + 2 * j + 0][hwl]);
                const unsigned hi = __float_as_uint(tile[oct * 8 + 2 * j + 1][hwl]);
                // round-to-nearest-even bf16 of two f32, packed
                const unsigned rlo = (lo + 0x7fffu + ((lo >> 16) & 1)) >> 16;
                const unsigned rhi = (hi + 0x7fffu + ((hi >> 16) & 1)) & 0xffff0000u;
                pk[j] = (rlo & 0xffffu) | rhi;
            }
            __builtin_nontemporal_store(pk,
                (uintv4*)((unsigned short*)ob + (size_t)hw * NCH + c0 + oct * 8));
        }
    }
}

// -------- per-point bilinear weight/offset computation (shared helper) --------
__device__ __forceinline__ void point_wo(
    float px, float py, float rx1, float ry1, float rx2, float ry2,
    float invS, int H, int W,
    float& w00, float& w01, float& w10, float& w11, unsigned& o00,
    unsigned& o01, unsigned& o10, unsigned& o11)
{
    const float cx = rx1 + px * (rx2 - rx1);
    const float cy = ry1 + py * (ry2 - ry1);
    // grid_sample align_corners=False collapses to coord/stride - 0.5
    const float x = cx * invS - 0.5f;
    const float y = cy * invS - 0.5f;

    const float x0f = floorf(x), y0f = floorf(y);
    const float wx1 = x - x0f, wx0 = 1.0f - wx1;
    const float wy1 = y - y0f, wy0 = 1.0f - wy1;
    const float x1f = x0f + 1.0f, y1f = y0f + 1.0f;

    const float vx0 = (x0f >= 0.0f && x0f <= (float)(W - 1)) ? 1.0f : 0.0f;
    const float vx1 = (x1f >= 0.0f && x1f <= (float)(W - 1)) ? 1.0f : 0.0f;
    const float vy0 = (y0f >= 0.0f && y0f <= (float)(H - 1)) ? 1.0f : 0.0f;
    const float vy1 = (y1f >= 0.0f && y1f <= (float)(H - 1)) ? 1.0f : 0.0f;

    const int x0 = min(max((int)x0f, 0), W - 1);
    const int x1 = min(max((int)x1f, 0), W - 1);
    const int y0 = min(max((int)y0f, 0), H - 1);
    const int y1 = min(max((int)y1f, 0), H - 1);

    w00 = wx0 * wy0 * vx0 * vy0;
    w01 = wx1 * wy0 * vx1 * vy0;
    w10 = wx0 * wy1 * vx0 * vy1;
    w11 = wx1 * wy1 * vx1 * vy1;

    o00 = ((unsigned)y0 * W + x0) * NCH;
    o01 = ((unsigned)y0 * W + x1) * NCH;
    o10 = ((unsigned)y1 * W + x0) * NCH;
    o11 = ((unsigned)y1 * W + x1) * NCH;
}

// ---------------- fused sample: all (roi, level, c-half) tuples ----------------
// block = (n, L, half); 256 threads = 16 channel-octets x 16 point-groups.
// Out stores are nontemporal (write-once) so the 205 MB stream doesn't evict
// the ws tap working set from L2.
__global__ __launch_bounds__(256) void sample_all(
    const __hip_bfloat16* __restrict__ ws,
    const float* __restrict__ rois,
    const float* __restrict__ points,
    float* __restrict__ out)
{
    __shared__ __align__(16) float tile[128 * NPTS];   // 25088 B

    const int bid  = blockIdx.x;
    const int n    = bid >> 3;
    const int rem  = ((bid & 7) + n) & 7;        // per-roi rotated (bijective)
    const int L    = rem >> 1;
    const int half = rem & 1;

    const __hip_bfloat16* ft;
    int H, W;
    float invS;
    if (L == 0)      { ft = ws;            H = 200; W = 336; invS = 0.25f;    }
    else if (L == 1) { ft = ws + 34406400; H = 100; W = 168; invS = 0.125f;   }
    else if (L == 2) { ft = ws + 43008000; H = 50;  W = 84;  invS = 0.0625f;  }
    else             { ft = ws + 45158400; H = 25;  W = 42;  invS = 0.03125f; }

    const int cl = (threadIdx.x & 15) * 8;       // local channel 0..120
    const int c  = half * 128 + cl;              // global channel
    const int pg = threadIdx.x >> 4;             // point group 0..15

    const float bi  = rois[n * 5 + 0];
    const float rx1 = rois[n * 5 + 1];
    const float ry1 = rois[n * 5 + 2];
    const float rx2 = rois[n * 5 + 3];
    const float ry2 = rois[n * 5 + 4];
    const int   b   = (int)bi;

    const unsigned short* fb =
        (const unsigned short*)(ft + (size_t)b * H * W * NCH);

    // ---- phase A: weights + offsets for all 3 points ----
    float w00[3], w01[3], w10[3], w11[3];
    unsigned o00[3], o01[3], o10[3], o11[3];
#pragma unroll
    for (int i = 0; i < 3; ++i) {
        const int p = pg + 16 * i;               // 49 = 3*16 + 1: p <= 47 here
        const float2 pt = *(const float2*)(points + ((size_t)n * NPTS + p) * 2);
        point_wo(pt.x, pt.y, rx1, ry1, rx2, ry2, invS, H, W,
                 w00[i], w01[i], w10[i], w11[i], o00[i], o01[i], o10[i], o11[i]);
    }

    // ---- phase B: issue all 12 tap loads back-to-back ----
    uint4 u00[3], u01[3], u10[3], u11[3];
#pragma unroll
    for (int i = 0; i < 3; ++i) {
        u00[i] = *(const uint4*)(fb + o00[i] + c);
        u01[i] = *(const uint4*)(fb + o01[i] + c);
        u10[i] = *(const uint4*)(fb + o10[i] + c);
        u11[i] = *(const uint4*)(fb + o11[i] + c);
    }

    // ---- phase C: FMA + LDS stores ----
#define ACCUM(UVEC, WGT) \
        acc[0] += bflo((UVEC).x) * (WGT); acc[1] += bfhi((UVEC).x) * (WGT); \
        acc[2] += bflo((UVEC).y) * (WGT); acc[3] += bfhi((UVEC).y) * (WGT); \
        acc[4] += bflo((UVEC).z) * (WGT); acc[5] += bfhi((UVEC).z) * (WGT); \
        acc[6] += bflo((UVEC).w) * (WGT); acc[7] += bfhi((UVEC).w) * (WGT);
#pragma unroll
    for (int i = 0; i < 3; ++i) {
        const int p = pg + 16 * i;
        float acc[8];
#pragma unroll
        for (int k = 0; k < 8; ++k) acc[k] = 0.0f;
        ACCUM(u00[i], w00[i])
        ACCUM(u01[i], w01[i])
        ACCUM(u10[i], w10[i])
        ACCUM(u11[i], w11[i])
#pragma unroll
        for (int k = 0; k < 8; ++k)
            tile[(cl + k) * NPTS + p] = acc[k];
    }

    // ---- tail point p = 48 (only channel-octet owners in group 0) ----
    if (pg == 0) {
        const float2 pt = *(const float2*)(points + ((size_t)n * NPTS + 48) * 2);
        float tw00, tw01, tw10, tw11;
        unsigned to00, to01, to10, to11;
        point_wo(pt.x, pt.y, rx1, ry1, rx2, ry2, invS, H, W,
                 tw00, tw01, tw10, tw11, to00, to01, to10, to11);
        const uint4 v00 = *(const uint4*)(fb + to00 + c);
        const uint4 v01 = *(const uint4*)(fb + to01 + c);
        const uint4 v10 = *(const uint4*)(fb + to10 + c);
        const uint4 v11 = *(const uint4*)(fb + to11 + c);
        float acc[8];
#pragma unroll
        for (int k = 0; k < 8; ++k) acc[k] = 0.0f;
        ACCUM(v00, tw00)
        ACCUM(v01, tw01)
        ACCUM(v10, tw10)
        ACCUM(v11, tw11)
#pragma unroll
        for (int k = 0; k < 8; ++k)
            tile[(cl + k) * NPTS + 48] = acc[k];
    }
#undef ACCUM
    __syncthreads();

    // contiguous 25 KB nontemporal write of the [128 x 49] half tile
    const floatv4* t4 = (const floatv4*)tile;
    floatv4* o4 = (floatv4*)(out + ((size_t)n * 1024 + (size_t)L * NCH + half * 128) * NPTS);
#pragma unroll 4
    for (int i = threadIdx.x; i < (128 * NPTS) / 4; i += 256)
        __builtin_nontemporal_store(t4[i], &o4[i]);
}

// ---------------- fallback: direct BCHW sampling (round-4 verified) ----------------
__global__ __launch_bounds__(256) void mpe_kernel(
    const float* __restrict__ f0, const float* __restrict__ f1,
    const float* __restrict__ f2, const float* __restrict__ f3,
    const float* __restrict__ rois, const float* __restrict__ points,
    float* __restrict__ out)
{
    const int np = blockIdx.x;
    const int n  = np / NPTS;
    const int p  = np - n * NPTS;
    const int c  = threadIdx.x;

    const float bi  = rois[n * 5 + 0];
    const float rx1 = rois[n * 5 + 1];
    const float ry1 = rois[n * 5 + 2];
    const float rx2 = rois[n * 5 + 3];
    const float ry2 = rois[n * 5 + 4];
    const int   b   = (int)bi;

    const float px = points[(size_t)np * 2 + 0];
    const float py = points[(size_t)np * 2 + 1];
    const float cx = rx1 + px * (rx2 - rx1);
    const float cy = ry1 + py * (ry2 - ry1);

    const float* feats[4] = {f0, f1, f2, f3};
    const int   Hs[4]   = {200, 100, 50, 25};
    const int   Ws[4]   = {336, 168, 84, 42};
    const float invS[4] = {0.25f, 0.125f, 0.0625f, 0.03125f};

#pragma unroll
    for (int L = 0; L < 4; ++L) {
        const int H = Hs[L], W = Ws[L];
        const float x = cx * invS[L] - 0.5f;
        const float y = cy * invS[L] - 0.5f;
        const float x0f = floorf(x), y0f = floorf(y);
        const float wx1 = x - x0f, wx0 = 1.0f - wx1;
        const float wy1 = y - y0f, wy0 = 1.0f - wy1;
        const float x1f = x0f + 1.0f, y1f = y0f + 1.0f;
        const float vx0 = (x0f >= 0.0f && x0f <= (float)(W - 1)) ? 1.0f : 0.0f;
        const float vx1 = (x1f >= 0.0f && x1f <= (float)(W - 1)) ? 1.0f : 0.0f;
        const float vy0 = (y0f >= 0.0f && y0f <= (float)(H - 1)) ? 1.0f : 0.0f;
        const float vy1 = (y1f >= 0.0f && y1f <= (float)(H - 1)) ? 1.0f : 0.0f;
        const int x0 = min(max((int)x0f, 0), W - 1);
        const int x1 = min(max((int)x1f, 0), W - 1);
        const int y0 = min(max((int)y0f, 0), H - 1);
        const int y1 = min(max((int)y1f, 0), H - 1);
        const float* base = feats[L] + ((size_t)b * NCH + c) * (size_t)(H * W);
        const float acc = base[y0 * W + x0] * (wx0 * wy0 * vx0 * vy0)
                        + base[y0 * W + x1] * (wx1 * wy0 * vx1 * vy0)
                        + base[y1 * W + x0] * (wx0 * wy1 * vx0 * vy1)
                        + base[y1 * W + x1] * (wx1 * wy1 * vx1 * vy1);
        out[((size_t)n * 1024 + (size_t)L * NCH + c) * NPTS + p] = acc;
    }
}

extern "C" void kernel_launch(void* const* d_in, const int* in_sizes, int n_in,
                              void* d_out, int out_size, void* d_ws, size_t ws_size,
                              hipStream_t stream)
{
    const float* f0     = (const float*)d_in[0];
    const float* f1     = (const float*)d_in[1];
    const float* f2     = (const float*)d_in[2];
    const float* f3     = (const float*)d_in[3];
    const float* rois   = (const float*)d_in[4];
    const float* points = (const float*)d_in[5];
    float*       out    = (float*)d_out;

    const size_t WS_NEED = 45696000ull * 2ull;   // 91.4 MB bf16 HWC copy

    if (ws_size >= WS_NEED) {
        __hip_bfloat16* ws = (__hip_bfloat16*)d_ws;
        transpose_all<<<dim3(5592), 256, 0, stream>>>(f0, f1, f2, f3, ws);
        sample_all<<<dim3(NROI * 8), 256, 0, stream>>>(ws, rois, points, out);
    } else {
        mpe_kernel<<<dim3(NROI * NPTS), 256, 0, stream>>>(f0, f1, f2, f3, rois, points, out);
    }
}